// Round 5
// baseline (1598.543 us; speedup 1.0000x reference)
//
#include <hip/hip_runtime.h>
#include <hip/hip_fp16.h>
#include <cmath>

#define HH 256
#define WW 256
#define TT 48
#define PLANE (HH * WW * TT)

#if defined(__has_builtin)
#if __has_builtin(__builtin_amdgcn_exp2f)
#define EXP2F(x) __builtin_amdgcn_exp2f(x)
#else
#define EXP2F(x) exp2f(x)
#endif
#else
#define EXP2F(x) exp2f(x)
#endif

typedef _Float16 half8 __attribute__((ext_vector_type(8)));
union F4 { float4 v; float f[4]; };

// pk[pixel] = {sg3, sg4, sg5, r6, s0, s1, s2, T} (fp16, 16 B)
//   sg_c = sqrt(sig_c*log2e)*g_c (c=3,4,5); r6 = ||sg|| over {0,1,2,6,7,8}
//   s_c  = sqrt(spp)*e_c;  T = T2*max_c(v_c)
__global__ __launch_bounds__(256)
void prep_pack(const float* __restrict__ guidance,
               const float* __restrict__ estimands,
               const float* __restrict__ variance,
               const float* __restrict__ sigma_inv,
               const int* __restrict__ spp_ptr,
               half8* __restrict__ pk)
{
    const int idx = ((int)blockIdx.x * 256 + (int)threadIdx.x) * 4;
    const float sppf = (float)(*spp_ptr);
    const float T2f  = 2.8070337683438042f * 2.8070337683438042f;
    const float sqs  = sqrtf(sppf);
    const float L2E  = 1.4426950408889634f;
    float sq[9];
#pragma unroll
    for (int g = 0; g < 9; ++g) sq[g] = sqrtf(sigma_inv[g] * L2E);

    F4 gg[9], ee[3], vv[3];
#pragma unroll
    for (int g = 0; g < 9; ++g) gg[g].v = *(const float4*)(guidance + (size_t)g * PLANE + idx);
#pragma unroll
    for (int c = 0; c < 3; ++c) {
        ee[c].v = *(const float4*)(estimands + (size_t)c * PLANE + idx);
        vv[c].v = *(const float4*)(variance  + (size_t)c * PLANE + idx);
    }
#pragma unroll
    for (int s = 0; s < 4; ++s) {
        float r6sq = 0.0f;
#pragma unroll
        for (int g = 0; g < 9; ++g) {
            if (g >= 3 && g < 6) continue;
            const float t = sq[g] * gg[g].f[s];
            r6sq = fmaf(t, t, r6sq);
        }
        half8 h;
        h[0] = (_Float16)(sq[3] * gg[3].f[s]);
        h[1] = (_Float16)(sq[4] * gg[4].f[s]);
        h[2] = (_Float16)(sq[5] * gg[5].f[s]);
        h[3] = (_Float16)sqrtf(r6sq);
        h[4] = (_Float16)(sqs * ee[0].f[s]);
        h[5] = (_Float16)(sqs * ee[1].f[s]);
        h[6] = (_Float16)(sqs * ee[2].f[s]);
        h[7] = (_Float16)(T2f * fmaxf(vv[0].f[s], fmaxf(vv[1].f[s], vv[2].f[s])));
        pk[idx + s] = h;
    }
}

// Thread owns 1 x-column x 8 t-centers. Block: 32 x * 6 tg = 192, grid (W/32, H).
__global__ __launch_bounds__(192, 3)
void stat_denoise(const float* __restrict__ images,
                  const float* __restrict__ guidance,
                  const float* __restrict__ estimands,
                  const float* __restrict__ variance,
                  const float* __restrict__ sigma_inv,
                  const int* __restrict__ spp_ptr,
                  const half8* __restrict__ pk,
                  float* __restrict__ out)
{
    const int tid = threadIdx.x;
    const int tg  = tid % 6;
    const int xl  = tid / 6;
    const int x   = (int)blockIdx.x * 32 + xl;
    const int y   = (int)blockIdx.y;
    const int t0  = tg * 8;

    const float sppf = (float)(*spp_ptr);
    const float T2f  = 2.8070337683438042f * 2.8070337683438042f;
    const float sqs  = sqrtf(sppf);
    const float L2E  = 1.4426950408889634f;
    float sq[9];
#pragma unroll
    for (int g = 0; g < 9; ++g) sq[g] = sqrtf(sigma_inv[g] * L2E);

    const int ccol  = (y * WW + x) * TT;
    const int cbase = ccol + t0;

    // ---- center quantities (exact fp32) ----
    float csg[3][8], cr6[8], cs[3][8], cTs[8];
    float num[3][8] = {}, den[8];
    {
        float ccF[8] = {}, r6sq[8] = {};
#pragma unroll
        for (int g = 0; g < 9; ++g) {
            F4 a, b;
            a.v = *(const float4*)(guidance + (size_t)g * PLANE + cbase);
            b.v = *(const float4*)(guidance + (size_t)g * PLANE + cbase + 4);
#pragma unroll
            for (int r = 0; r < 8; ++r) {
                const float s = sq[g] * (r < 4 ? a.f[r] : b.f[r - 4]);
                ccF[r] = fmaf(s, s, ccF[r]);
                if (g >= 3 && g < 6) csg[g - 3][r] = s;
                else                 r6sq[r] = fmaf(s, s, r6sq[r]);
            }
        }
#pragma unroll
        for (int r = 0; r < 8; ++r) cr6[r] = sqrtf(r6sq[r]);

        float maxv[8];
        bool okpad[8] = {true, true, true, true, true, true, true, true};
#pragma unroll
        for (int c = 0; c < 3; ++c) {
            F4 ea, eb, va, vb;
            ea.v = *(const float4*)(estimands + (size_t)c * PLANE + cbase);
            eb.v = *(const float4*)(estimands + (size_t)c * PLANE + cbase + 4);
            va.v = *(const float4*)(variance  + (size_t)c * PLANE + cbase);
            vb.v = *(const float4*)(variance  + (size_t)c * PLANE + cbase + 4);
#pragma unroll
            for (int r = 0; r < 8; ++r) {
                const float ec = (r < 4 ? ea.f[r] : eb.f[r - 4]);
                const float vc = (r < 4 ? va.f[r] : vb.f[r - 4]);
                cs[c][r] = sqs * ec;
                maxv[r] = (c == 0) ? vc : fmaxf(maxv[r], vc);
                const float dd = -2.0f - ec;
                okpad[r] = okpad[r] && ((dd * dd) * sppf <= T2f * vc);
            }
        }
        const int cnty = 7 - max(0, 3 - y) - max(0, y + 3 - (HH - 1));
        const int cntx = 7 - max(0, 3 - x) - max(0, x + 3 - (WW - 1));
#pragma unroll
        for (int r = 0; r < 8; ++r) {
            cTs[r] = fmaf(T2f, maxv[r], 0.5f);      // T_c + z-slack
            const int t = t0 + r;
            const int cntt = 5 - max(0, 2 - t) - max(0, t + 2 - (TT - 1));
            const float n_oob = (float)(245 - cnty * cntx * cntt);
            den[r] = 1.0f + (okpad[r] ? n_oob * EXP2F(-ccF[r]) : 0.0f); // self + pad
        }
    }

    int tcl[12];
    unsigned tvm = 0;
#pragma unroll
    for (int k = 0; k < 12; ++k) {
        const int t = t0 - 2 + k;
        tcl[k] = min(max(t, 0), TT - 1);
        tvm |= ((unsigned)(t >= 0 && t < TT)) << k;
    }

    const float DC = 26.5f;   // 25 (w<2^-25 drop) + fp16 slack

    for (int dy = -3; dy <= 3; ++dy) {
        const int yy  = y + dy;
        const int ycl = min(max(yy, 0), HH - 1);
        const bool yok = (yy == ycl);
        for (int j = 0; j < 7; ++j) {
            const int xx  = x + j - 3;
            const int xcl = min(max(xx, 0), WW - 1);
            const bool cok = yok && (xx == xcl);
            const int nco = (ycl * WW + xcl) * TT;
            const half8* base = pk + nco;

            unsigned mask0 = 0, mask1 = 0;
#pragma unroll
            for (int k = 0; k < 12; ++k) {
                const half8 h = base[tcl[k]];
                const bool vk = cok && ((tvm >> k) & 1u);
                const float ns3 = (float)h[0];
                const float ns4 = (float)h[1];
                const float ns5 = (float)h[2];
                const float nr6 = vk ? (float)h[3] : 3.0e4f;  // poison -> m << 0
                const float ns0 = (float)h[4];
                const float ns1 = (float)h[5];
                const float ns2 = (float)h[6];
                const float nT  = (float)h[7];
#pragma unroll
                for (int r = 0; r < 8; ++r) {
                    const int d = k - r;
                    if (d < 0 || d > 4) continue;
                    const float d0 = ns3 - csg[0][r];
                    const float d1 = ns4 - csg[1][r];
                    const float d2 = ns5 - csg[2][r];
                    float dist3 = d0 * d0;
                    dist3 = fmaf(d1, d1, dist3);
                    dist3 = fmaf(d2, d2, dist3);
                    const float dr = nr6 - cr6[r];
                    float m = DC - fmaf(dr, dr, dist3);
                    const float ts = nT + cTs[r];
                    const float e0 = ns0 - cs[0][r];
                    m = fminf(m, fmaf(-e0, e0, ts));
                    const float e1 = ns1 - cs[1][r];
                    m = fminf(m, fmaf(-e1, e1, ts));
                    const float e2 = ns2 - cs[2][r];
                    m = fminf(m, fmaf(-e2, e2, ts));
                    const int idx = r * 5 + d;
                    if (idx < 20) mask0 |= (m >= 0.0f) ? (1u << idx) : 0u;
                    else          mask1 |= (m >= 0.0f) ? (1u << (idx - 20)) : 0u;
                }
            }
            if (dy == 0 && j == 3) {      // self pairs (d==2) analytic
                mask0 &= ~0x21084u;
                mask1 &= ~0x21084u;
            }

            unsigned long long mm = ((unsigned long long)mask1 << 20) | (unsigned long long)mask0;
            while (mm) {
                const int idx = (int)__builtin_ctzll(mm);
                mm &= mm - 1;
                const int r  = (idx * 13) >> 6;     // idx/5 for idx<40
                const int d  = idx - r * 5;
                const int tc = t0 + r;
                const int tn = tc + d - 2;
                float dist = 0.0f;
#pragma unroll
                for (int g = 0; g < 9; ++g) {
                    const float gn = guidance[(size_t)g * PLANE + nco + tn];
                    const float gc = guidance[(size_t)g * PLANE + ccol + tc];
                    const float df = sq[g] * (gn - gc);
                    dist = fmaf(df, df, dist);
                }
                bool pass = true;
#pragma unroll
                for (int c = 0; c < 3; ++c) {
                    const float en = estimands[(size_t)c * PLANE + nco + tn];
                    const float ec = estimands[(size_t)c * PLANE + ccol + tc];
                    const float vn = variance [(size_t)c * PLANE + nco + tn];
                    const float vc = variance [(size_t)c * PLANE + ccol + tc];
                    const float de = en - ec;
                    pass = pass && ((de * de) * sppf <= T2f * (vn + vc));
                }
                const float w = pass ? EXP2F(-dist) : 0.0f;
                const float w0 = w * images[0 * (size_t)PLANE + nco + tn];
                const float w1 = w * images[1 * (size_t)PLANE + nco + tn];
                const float w2 = w * images[2 * (size_t)PLANE + nco + tn];
                switch (r) {
                  case 0: den[0]+=w; num[0][0]+=w0; num[1][0]+=w1; num[2][0]+=w2; break;
                  case 1: den[1]+=w; num[0][1]+=w0; num[1][1]+=w1; num[2][1]+=w2; break;
                  case 2: den[2]+=w; num[0][2]+=w0; num[1][2]+=w1; num[2][2]+=w2; break;
                  case 3: den[3]+=w; num[0][3]+=w0; num[1][3]+=w1; num[2][3]+=w2; break;
                  case 4: den[4]+=w; num[0][4]+=w0; num[1][4]+=w1; num[2][4]+=w2; break;
                  case 5: den[5]+=w; num[0][5]+=w0; num[1][5]+=w1; num[2][5]+=w2; break;
                  case 6: den[6]+=w; num[0][6]+=w0; num[1][6]+=w1; num[2][6]+=w2; break;
                  default:den[7]+=w; num[0][7]+=w0; num[1][7]+=w1; num[2][7]+=w2; break;
                }
            }
        }
    }

    // epilogue: out = (num + img_center) / den
    F4 ia[3], ib[3];
#pragma unroll
    for (int c = 0; c < 3; ++c) {
        ia[c].v = *(const float4*)(images + (size_t)c * PLANE + cbase);
        ib[c].v = *(const float4*)(images + (size_t)c * PLANE + cbase + 4);
    }
    float rcd[8];
#pragma unroll
    for (int r = 0; r < 8; ++r) rcd[r] = 1.0f / den[r];
#pragma unroll
    for (int c = 0; c < 3; ++c) {
        F4 oa, ob;
#pragma unroll
        for (int r = 0; r < 8; ++r) {
            const float ic = (r < 4 ? ia[c].f[r] : ib[c].f[r - 4]);
            const float o  = (num[c][r] + ic) * rcd[r];
            if (r < 4) oa.f[r] = o; else ob.f[r - 4] = o;
        }
        *(float4*)(out + (size_t)c * PLANE + cbase)     = oa.v;
        *(float4*)(out + (size_t)c * PLANE + cbase + 4) = ob.v;
    }
}

extern "C" void kernel_launch(void* const* d_in, const int* in_sizes, int n_in,
                              void* d_out, int out_size, void* d_ws, size_t ws_size,
                              hipStream_t stream)
{
    (void)in_sizes; (void)n_in; (void)out_size; (void)ws_size;
    const float* images    = (const float*)d_in[0];
    const float* guidance  = (const float*)d_in[1];
    const float* estimands = (const float*)d_in[2];
    const float* variance  = (const float*)d_in[3];
    const float* sigma_inv = (const float*)d_in[4];
    const int*   spp       = (const int*)d_in[5];
    half8* pk = (half8*)d_ws;                       // PLANE * 16 B = 50.3 MB

    hipLaunchKernelGGL(prep_pack, dim3(PLANE / 1024), dim3(256), 0, stream,
                       guidance, estimands, variance, sigma_inv, spp, pk);
    hipLaunchKernelGGL(stat_denoise, dim3(WW / 32, HH), dim3(192), 0, stream,
                       images, guidance, estimands, variance, sigma_inv, spp, pk,
                       (float*)d_out);
}